// Round 1
// 1956.876 us; speedup vs baseline: 1.0889x; 1.0889x over previous
//
#include <hip/hip_runtime.h>

typedef unsigned short u16;
typedef unsigned int   u32;
typedef unsigned long long u64;
typedef __attribute__((ext_vector_type(8))) short short8;   // 8 x bf16 (4 VGPR)
typedef __attribute__((ext_vector_type(4))) float f32x4;

#define NB   64      // batch
#define TS   512     // timesteps
#define HD   512     // hidden
#define RG   4       // row-groups (16 batch rows each)
#define CG   16      // col-groups (32 h-cols each)
#define NBLK (RG*CG) // 64 persistent blocks, 512 threads each
#define HROW 256     // tagged u64 per h row (2 bf16 + tag per u64)
#define SLOT (NB*HROW)

__device__ __forceinline__ u16 f2bf(float x) {
    union { float f; u32 i; } v; v.f = x;
    u32 r = (v.i + 0x7fffu + ((v.i >> 16) & 1u)) >> 16;
    return (u16)r;
}
__device__ __forceinline__ u32 pack2bf(float a, float b) {
    return (u32)f2bf(a) | ((u32)f2bf(b) << 16);
}
__device__ __forceinline__ float sigmf(float x) { return 1.0f / (1.0f + __expf(-x)); }
__device__ __forceinline__ float tanhf_fast(float x) { return 1.0f - 2.0f / (__expf(2.0f * x) + 1.0f); }

// ---- x: f32 -> bf16, elementwise (one-time) -------------------------------
__global__ void cvt_x_k(const float* __restrict__ in, u16* __restrict__ out, int n) {
    int i = (blockIdx.x * blockDim.x + threadIdx.x) * 8;
    const int stride = gridDim.x * blockDim.x * 8;
    for (; i < n; i += stride) {
        const f32x4 a = *(const f32x4*)(in + i);
        const f32x4 b = *(const f32x4*)(in + i + 4);
        u32 q[4];
        q[0] = pack2bf(a[0], a[1]);
        q[1] = pack2bf(a[2], a[3]);
        q[2] = pack2bf(b[0], b[1]);
        q[3] = pack2bf(b[2], b[3]);
        *(f32x4*)(out + i) = *(f32x4*)q;   // 16B store of 8 bf16
    }
}

// ---- transpose + f32->bf16 convert: in (R x C) f32 -> out (C x R) bf16 ----
__global__ void transpose_cvt_k(const float* __restrict__ in, u16* __restrict__ out,
                                int R, int C) {
    __shared__ float tile[32][33];
    const int c0 = blockIdx.x * 32;
    const int r0 = blockIdx.y * 32;
    const int tx = threadIdx.x & 31;
    const int ty = threadIdx.x >> 5;    // 0..7
#pragma unroll
    for (int i = 0; i < 32; i += 8)
        tile[ty + i][tx] = in[(size_t)(r0 + ty + i) * C + c0 + tx];
    __syncthreads();
#pragma unroll
    for (int i = 0; i < 32; i += 8)
        out[(size_t)(c0 + ty + i) * R + r0 + tx] = f2bf(tile[tx][ty + i]);
}

// ---- persistent fused LSTM ------------------------------------------------
// 64 blocks (r=bid&3 row-group of 16 batch rows, cg=bid>>2 col-group of 32 h-cols).
// 8 waves: gate g = wv&3, K-half kh = wv>>2. Per wave: two 16x16 output tiles
// over K=256 (16 x-MFMA + 16 h-MFMA).
// h transport: SELF-VALIDATING tagged u64 words (2 bf16 << 32 | (t+1)) via
// relaxed agent atomics. No flags, no producer drain, poll==data-load.
// Ring of 4 slots; max producer lead inside a chain is 1 slot -> race-free.
__global__ __launch_bounds__(512, 2) void lstm_fused(
    const u16*   __restrict__ xbg,  // (64,512,512) bf16
    const u16*   __restrict__ WtX,  // (2048,512) bf16 = W_xh^T
    const u16*   __restrict__ WtH,  // (2048,512) bf16 = W_hh^T
    const float* __restrict__ bxh,  // (2048) f32
    const float* __restrict__ bhh,  // (2048) f32
    u64*   __restrict__ hbuf,       // ring: (4 slots, 64 rows, 256 tagged u64)
    float* __restrict__ y)          // (64,512,512) f32
{
    const int bid  = blockIdx.x;
    const int r    = bid & 3;
    const int cg   = bid >> 2;          // 0..15
    const int tid  = threadIdx.x;
    const int lane = tid & 63;
    const int wv   = tid >> 6;          // 0..7
    const int g    = wv & 3;            // gate
    const int kh   = wv >> 2;           // K-half 0..1
    const int m15  = lane & 15;
    const int kq   = lane >> 4;         // 0..3
    const int n0   = r * 16;
    const int gcol0 = g * 512 + cg * 32;
    const int kbase = kh * 256;         // bf16-element K offset

    __shared__ __align__(16) u32 ldsH[16 * 256];       // 16 rows x 1KB, XOR-swizzled
    __shared__ float gbuf2[2][4][16][34];              // [kh][gate][row][col] partials

    // --- preload W fragments (B-operand: n = gcol0 + c*16 + m15, k = kbase+kc*32+kq*8+j)
    short8 wx[2][8], wh[2][8];
#pragma unroll
    for (int c = 0; c < 2; ++c) {
        const u16* px = WtX + (size_t)(gcol0 + c * 16 + m15) * 512 + kbase + kq * 8;
        const u16* ph = WtH + (size_t)(gcol0 + c * 16 + m15) * 512 + kbase + kq * 8;
#pragma unroll
        for (int kc = 0; kc < 8; ++kc) {
            wx[c][kc] = *(const short8*)(px + kc * 32);
            wh[c][kc] = *(const short8*)(ph + kc * 32);
        }
    }

    // elementwise ownership: 512 threads -> 16 rows x 32 h-cols
    const int erow = tid >> 5;
    const int ecol = tid & 31;
    const int hcol = cg * 32 + ecol;
    const float bI = bxh[hcol]        + bhh[hcol];
    const float bF = bxh[512  + hcol] + bhh[512  + hcol];
    const float bG = bxh[1024 + hcol] + bhh[1024 + hcol];
    const float bO = bxh[1536 + hcol] + bhh[1536 + hcol];
    float cst = 0.0f;

    // consumer staging: wave wv covers rows {2wv, 2wv+1}; lane lq covers u64 col lq+32i
    const int lrow = 2 * wv + (lane >> 5);
    const int lq   = lane & 31;
    const int swzw = (lrow & 7) << 2;   // word-granular XOR (16B..64B bits)

    // ---- seed x fragments for t=0 (A-frag: row=m15, k=kbase+kc*32+kq*8+j)
    short8 xb[8];
    {
        const u16* xg = xbg + (size_t)(n0 + m15) * TS * HD + kbase + kq * 8;
#pragma unroll
        for (int kc = 0; kc < 8; ++kc) xb[kc] = *(const short8*)(xg + kc * 32);
    }

    for (int t = 0; t < TS; ++t) {
        u64 hq[8];
        const u64* gsrc = hbuf + (size_t)((t - 1) & 3) * SLOT
                        + (size_t)(n0 + lrow) * HROW + lq;
        if (t > 0) {
            // issue poll/data loads (coalesced: 32 lanes x 8B contiguous per instr)
#pragma unroll
            for (int i = 0; i < 8; ++i)
                hq[i] = __hip_atomic_load(gsrc + i * 32, __ATOMIC_RELAXED,
                                          __HIP_MEMORY_SCOPE_AGENT);
        }

        // ---- x-part MFMA (overlaps first poll round-trip)
        f32x4 a00 = {0.f,0.f,0.f,0.f}, a01 = {0.f,0.f,0.f,0.f};
        f32x4 a10 = {0.f,0.f,0.f,0.f}, a11 = {0.f,0.f,0.f,0.f};
#pragma unroll
        for (int kc = 0; kc < 8; kc += 2) {
            a00 = __builtin_amdgcn_mfma_f32_16x16x32_bf16(xb[kc],   wx[0][kc],   a00, 0, 0, 0);
            a10 = __builtin_amdgcn_mfma_f32_16x16x32_bf16(xb[kc],   wx[1][kc],   a10, 0, 0, 0);
            a01 = __builtin_amdgcn_mfma_f32_16x16x32_bf16(xb[kc+1], wx[0][kc+1], a01, 0, 0, 0);
            a11 = __builtin_amdgcn_mfma_f32_16x16x32_bf16(xb[kc+1], wx[1][kc+1], a11, 0, 0, 0);
        }

        if (t > 0) {
            // ---- tag check; on success the payload is already in registers
            const u32 tagv = (u32)t;
            for (;;) {
                u32 stale = 0;
#pragma unroll
                for (int i = 0; i < 8; ++i) stale |= ((u32)hq[i]) ^ tagv;
                if (__all(stale == 0)) break;
                __builtin_amdgcn_s_sleep(1);
#pragma unroll
                for (int i = 0; i < 8; ++i)
                    hq[i] = __hip_atomic_load(gsrc + i * 32, __ATOMIC_RELAXED,
                                              __HIP_MEMORY_SCOPE_AGENT);
            }
            // ---- share via swizzled LDS (conflict-free b32 writes)
#pragma unroll
            for (int i = 0; i < 8; ++i)
                ldsH[lrow * 256 + ((i * 32 + lq) ^ swzw)] = (u32)(hq[i] >> 32);
            __syncthreads();                                   // B1

            // ---- h-part MFMA from swizzled LDS A-frags
            const u32* lbase = ldsH + m15 * 256;
            const int swzr = (m15 & 7) << 2;
#pragma unroll
            for (int kc = 0; kc < 8; kc += 2) {
                short8 h0 = *(const short8*)(lbase + (((kbase >> 1) + kc * 16 + kq * 4) ^ swzr));
                short8 h1 = *(const short8*)(lbase + (((kbase >> 1) + (kc + 1) * 16 + kq * 4) ^ swzr));
                a00 = __builtin_amdgcn_mfma_f32_16x16x32_bf16(h0, wh[0][kc],   a00, 0, 0, 0);
                a10 = __builtin_amdgcn_mfma_f32_16x16x32_bf16(h0, wh[1][kc],   a10, 0, 0, 0);
                a01 = __builtin_amdgcn_mfma_f32_16x16x32_bf16(h1, wh[0][kc+1], a01, 0, 0, 0);
                a11 = __builtin_amdgcn_mfma_f32_16x16x32_bf16(h1, wh[1][kc+1], a11, 0, 0, 0);
            }
        }

        // ---- merge partials into LDS (C/D layout: col=lane&15, row=kq*4+j)
        {
            const f32x4 s0 = a00 + a01;
            const f32x4 s1 = a10 + a11;
#pragma unroll
            for (int j = 0; j < 4; ++j) {
                gbuf2[kh][g][kq * 4 + j][m15]      = s0[j];
                gbuf2[kh][g][kq * 4 + j][16 + m15] = s1[j];
            }
        }
        __syncthreads();                                       // B2

        // ---- elementwise LSTM cell (1 element per thread) + direct tagged publish
        {
            const float gi = gbuf2[0][0][erow][ecol] + gbuf2[1][0][erow][ecol] + bI;
            const float gf = gbuf2[0][1][erow][ecol] + gbuf2[1][1][erow][ecol] + bF;
            const float gg = gbuf2[0][2][erow][ecol] + gbuf2[1][2][erow][ecol] + bG;
            const float go = gbuf2[0][3][erow][ecol] + gbuf2[1][3][erow][ecol] + bO;
            const float iv = sigmf(gi);
            const float fv = sigmf(gf);
            const float gv = tanhf_fast(gg);
            const float ov = sigmf(go);
            cst = fv * cst + iv * gv;
            const float hv = ov * tanhf_fast(cst);
            y[((size_t)(n0 + erow) * TS + t) * HD + hcol] = hv;   // f32 output

            const u32 me = (u32)f2bf(hv);
            const u32 nb = (u32)__shfl_xor((int)me, 1);
            if ((ecol & 1) == 0) {
                const u64 v = ((u64)(me | (nb << 16)) << 32) | (u64)(u32)(t + 1);
                __hip_atomic_store(hbuf + (size_t)(t & 3) * SLOT
                                   + (size_t)(n0 + erow) * HROW + cg * 16 + (ecol >> 1),
                                   v, __ATOMIC_RELAXED, __HIP_MEMORY_SCOPE_AGENT);
            }
        }

        // ---- prefetch x fragments for t+1 (overlaps next poll)
        if (t + 1 < TS) {
            const u16* xg = xbg + ((size_t)(n0 + m15) * TS + (t + 1)) * HD + kbase + kq * 8;
#pragma unroll
            for (int kc = 0; kc < 8; ++kc) xb[kc] = *(const short8*)(xg + kc * 32);
        }
    }
}

extern "C" void kernel_launch(void* const* d_in, const int* in_sizes, int n_in,
                              void* d_out, int out_size, void* d_ws, size_t ws_size,
                              hipStream_t stream) {
    const float* x   = (const float*)d_in[0];
    const float* wxh = (const float*)d_in[1];
    const float* whh = (const float*)d_in[2];
    const float* bxh = (const float*)d_in[3];
    const float* bhh = (const float*)d_in[4];
    float* y = (float*)d_out;

    char* ws = (char*)d_ws;
    u64* hbuf = (u64*)ws;                                     // 512 KB ring (4 slots)
    u16* WtX  = (u16*)(ws + (size_t)(1 << 19));               // 2 MB
    u16* WtH  = (u16*)(ws + (size_t)(1 << 19) + (size_t)2048 * 512 * 2);
    u16* xbg  = (u16*)(ws + (size_t)(1 << 19) + (size_t)2 * 2048 * 512 * 2);  // 32 MB

    // zero the ring: kills cross-launch tag ABA (tags restart at 1 each launch)
    (void)hipMemsetAsync(hbuf, 0, (size_t)4 * SLOT * sizeof(u64), stream);

    cvt_x_k<<<2048, 256, 0, stream>>>(x, xbg, NB * TS * HD);

    dim3 tgrid(2048 / 32, 512 / 32);
    transpose_cvt_k<<<tgrid, 256, 0, stream>>>(wxh, WtX, 512, 2048);
    transpose_cvt_k<<<tgrid, 256, 0, stream>>>(whh, WtH, 512, 2048);

    lstm_fused<<<dim3(NBLK), dim3(512), 0, stream>>>(xbg, WtX, WtH, bxh, bhh,
                                                     hbuf, y);
}